// Round 5
// baseline (128.760 us; speedup 1.0000x reference)
//
#include <hip/hip_runtime.h>

// ConvCaps2D + dynamic routing, one fused kernel. R5 = R4 structure with
// relaxed __launch_bounds__(512, 2) so the allocator keeps the ~96-reg
// working set in VGPRs instead of clamping to the 64-granule and spilling.
// 512 thr/block, 1 site/block (1800 sites). Thread (o, eh, nl):
//   o  = t>>5     : output channel 0..15
//   eh = (t>>4)&1 : element-half (pose rows 2eh, 2eh+1 -> 8 elems)
//   nl = t&15     : vote lane; owns n = nl + 16j, j=0..8 (144 exact, no tail)
// Votes packed bf16 pairs: vp[9][4] u32. Softmax over o via exp(b)/den,
// den accumulated with LDS atomicAdd (no max-sub; |b| stays small here).

#define OH 15
#define OW 15
#define VPT 9

__device__ __forceinline__ unsigned int bf16rne(float f) {
    unsigned int x = __float_as_uint(f);
    return (x + 0x7fffu + ((x >> 16) & 1u)) >> 16;   // round-nearest-even
}
__device__ __forceinline__ float bf_lo(unsigned int pk) {
    return __uint_as_float(pk << 16);
}
__device__ __forceinline__ float bf_hi(unsigned int pk) {
    return __uint_as_float(pk & 0xffff0000u);
}

__global__ __launch_bounds__(512, 2)
void convcaps_kernel(const float* __restrict__ poses,
                     const float* __restrict__ kern,
                     float* __restrict__ out)
{
    __shared__ float den[2][144];

    const int site = blockIdx.x;                    // 0..1799
    const int b    = site / (OH * OW);
    const int rem  = site % (OH * OW);
    const int h    = rem / OW;
    const int w    = rem % OW;

    const int t  = threadIdx.x;
    const int o  = t >> 5;
    const int eh = (t >> 4) & 1;
    const int nl = t & 15;

    if (t < 288) ((float*)den)[t] = 0.0f;

    // ---- votes: rows (2eh, 2eh+1) of vote[o][n], n = nl+16j -> kl=j, c=nl ----
    unsigned int vp[VPT][4];
    const float* pbase = poses + (size_t)b * (32 * 32 * 256);
    #pragma unroll
    for (int j = 0; j < VPT; ++j) {
        const int y = 2 * h + j / 3;
        const int x = 2 * w + j % 3;
        const float* pp = pbase + (size_t)(y * 32 + x) * 256 + nl * 16 + eh * 8;
        const float4 pA = reinterpret_cast<const float4*>(pp)[0];   // row 2eh
        const float4 pB = reinterpret_cast<const float4*>(pp)[1];   // row 2eh+1
        const float* Kp = kern + (((size_t)(o * 9 + j) * 16 + nl) << 4);
        const float4 k0 = reinterpret_cast<const float4*>(Kp)[0];
        const float4 k1 = reinterpret_cast<const float4*>(Kp)[1];
        const float4 k2 = reinterpret_cast<const float4*>(Kp)[2];
        const float4 k3 = reinterpret_cast<const float4*>(Kp)[3];
        const float a0 = pA.x*k0.x + pA.y*k1.x + pA.z*k2.x + pA.w*k3.x;
        const float a1 = pA.x*k0.y + pA.y*k1.y + pA.z*k2.y + pA.w*k3.y;
        const float a2 = pA.x*k0.z + pA.y*k1.z + pA.z*k2.z + pA.w*k3.z;
        const float a3 = pA.x*k0.w + pA.y*k1.w + pA.z*k2.w + pA.w*k3.w;
        const float b0 = pB.x*k0.x + pB.y*k1.x + pB.z*k2.x + pB.w*k3.x;
        const float b1 = pB.x*k0.y + pB.y*k1.y + pB.z*k2.y + pB.w*k3.y;
        const float b2 = pB.x*k0.z + pB.y*k1.z + pB.z*k2.z + pB.w*k3.z;
        const float b3 = pB.x*k0.w + pB.y*k1.w + pB.z*k2.w + pB.w*k3.w;
        vp[j][0] = bf16rne(a0) | (bf16rne(a1) << 16);
        vp[j][1] = bf16rne(a2) | (bf16rne(a3) << 16);
        vp[j][2] = bf16rne(b0) | (bf16rne(b1) << 16);
        vp[j][3] = bf16rne(b2) | (bf16rne(b3) << 16);
    }
    __syncthreads();   // den zeros visible before first atomicAdd

    float e_[VPT];     // exp(b[o][n])
    float c_[VPT];     // coupling coefficients
    #pragma unroll
    for (int j = 0; j < VPT; ++j) { e_[j] = 1.0f; c_[j] = 0.0625f; }

    float s[8];        // own 8 elems: partial s, then squashed v
    float sq = 0.0f, fac = 0.0f;

    #pragma unroll
    for (int iter = 0; iter < 3; ++iter) {
        // s[o][own elems] = sum_n c * vote
        #pragma unroll
        for (int e = 0; e < 8; ++e) s[e] = 0.0f;
        #pragma unroll
        for (int j = 0; j < VPT; ++j) {
            const float c = c_[j];
            #pragma unroll
            for (int pr = 0; pr < 4; ++pr) {
                const unsigned int pk = vp[j][pr];
                s[2 * pr + 0] += c * bf_lo(pk);
                s[2 * pr + 1] += c * bf_hi(pk);
            }
        }
        // reduce over the 16 nl-lanes
        #pragma unroll
        for (int m = 1; m <= 8; m <<= 1) {
            #pragma unroll
            for (int e = 0; e < 8; ++e) s[e] += __shfl_xor(s[e], m, 64);
        }
        // squash
        float sqh = 0.0f;
        #pragma unroll
        for (int e = 0; e < 8; ++e) sqh += s[e] * s[e];
        sq = sqh + __shfl_xor(sqh, 16, 64);
        fac = sq * __builtin_amdgcn_rcpf(1.0f + sq) * rsqrtf(sq + 1e-9f);
        #pragma unroll
        for (int e = 0; e < 8; ++e) s[e] *= fac;          // s = v

        if (iter < 2) {
            // b += dot(v, vote); den[n] = sum_o exp(b)
            #pragma unroll
            for (int j = 0; j < VPT; ++j) {
                float d = 0.0f;
                #pragma unroll
                for (int pr = 0; pr < 4; ++pr) {
                    const unsigned int pk = vp[j][pr];
                    d += s[2 * pr + 0] * bf_lo(pk);
                    d += s[2 * pr + 1] * bf_hi(pk);
                }
                d += __shfl_xor(d, 16, 64);               // full 16-elem dot
                e_[j] *= __expf(d);
                if (eh == 0) atomicAdd(&den[iter][nl + 16 * j], e_[j]);
            }
            __syncthreads();
            #pragma unroll
            for (int j = 0; j < VPT; ++j)
                c_[j] = e_[j] * __builtin_amdgcn_rcpf(den[iter][nl + 16 * j]);
        }
    }

    // ---- output ----
    // capsule_poses [8,15,15,16,4,4]: elem = eh*8 + k, lane nl==k (k<8) writes
    float vout = s[0];
    #pragma unroll
    for (int k = 1; k < 8; ++k) {
        if (nl == k) vout = s[k];
    }
    if (nl < 8)
        out[(size_t)site * 256 + o * 16 + eh * 8 + nl] = vout;

    // capsule_activations [8,15,15,16]: ||v|| = sqrt(sq*fac^2 + 1e-12)
    if (nl == 8 && eh == 0)
        out[460800 + (size_t)site * 16 + o] = sqrtf(sq * fac * fac + 1e-12f);
}

extern "C" void kernel_launch(void* const* d_in, const int* in_sizes, int n_in,
                              void* d_out, int out_size, void* d_ws, size_t ws_size,
                              hipStream_t stream) {
    const float* poses = (const float*)d_in[0];   // [8,32,32,16,4,4] f32
    // d_in[1] = input_activations: unused by the reference computation
    const float* kern  = (const float*)d_in[2];   // [16,3,3,16,4,4] f32
    float* outp = (float*)d_out;                  // 460800 poses + 28800 acts

    convcaps_kernel<<<dim3(8 * OH * OW), dim3(512), 0, stream>>>(
        poses, kern, outp);
}

// Round 6
// 48.116 us; speedup vs baseline: 2.6760x; 2.6760x over previous
//
#include <hip/hip_runtime.h>

// ConvCaps2D with dynamic routing, fused single kernel. R6 = R1 structure
// (proven 45us) with ONE change: votes stored as packed bf16 pairs
// (vp[9][8] u32 = 72 regs instead of 144 f32) via plain-C RNE packing,
// targeting the 128-reg occupancy cliff (2 -> 4 waves/SIMD).
// B=8, 32x32x16 poses 4x4, 3x3 stride-2 VALID -> oh=ow=15, O=16, N=144.

#define OH 15
#define OW 15
#define N_VOTES 144
#define VPT 9            // votes per thread: 16*144/256
#define POSE_PAD 20      // LDS row stride for pose rows
#define B_PAD 17         // LDS row stride for b[n][o]

__device__ __forceinline__ unsigned int bf16rne(float f) {
    unsigned int x = __float_as_uint(f);
    return (x + 0x7fffu + ((x >> 16) & 1u)) >> 16;   // round-nearest-even
}
__device__ __forceinline__ float bf_lo(unsigned int pk) {
    return __uint_as_float(pk << 16);
}
__device__ __forceinline__ float bf_hi(unsigned int pk) {
    return __uint_as_float(pk & 0xffff0000u);
}

__global__ __launch_bounds__(256, 2)
void convcaps_routing_kernel(const float* __restrict__ poses,
                             const float* __restrict__ kern,
                             float* __restrict__ out)
{
    __shared__ float pose_lds[N_VOTES * POSE_PAD]; // 11520 B
    __shared__ float b_lds[N_VOTES * B_PAD];       // 9792 B
    __shared__ float nmax[N_VOTES];
    __shared__ float rden[N_VOTES];

    const int site = blockIdx.x;                   // 0..1799
    const int b    = site / (OH * OW);
    const int rem  = site % (OH * OW);
    const int h    = rem / OW;
    const int w    = rem % OW;

    const int t  = threadIdx.x;
    const int o  = t >> 4;                         // output channel 0..15
    const int nt = t & 15;                         // base vote index

    // ---- stage 144 pose matrices into LDS, float4 coalesced ----
    const float* pbase = poses + (size_t)b * (32 * 32 * 256);
    for (int idx = t; idx < N_VOTES * 4; idx += 256) {
        int n  = idx >> 2;
        int e4 = idx & 3;
        int kl = n >> 4;
        int c  = n & 15;
        int k  = kl / 3, l = kl % 3;
        int y  = 2 * h + k, x = 2 * w + l;
        const float4 v = *reinterpret_cast<const float4*>(
            pbase + (size_t)(y * 32 + x) * 256 + c * 16 + e4 * 4);
        *reinterpret_cast<float4*>(&pose_lds[n * POSE_PAD + e4 * 4]) = v;
    }
    __syncthreads();

    // ---- votes -> packed bf16 pairs in registers (plain C pack) ----
    unsigned int vp[VPT][8];
    #pragma unroll
    for (int j = 0; j < VPT; ++j) {
        const int n = nt + 16 * j;
        const float* Kp = kern + ((size_t)(o * N_VOTES + n) << 4);
        const float4 k0 = reinterpret_cast<const float4*>(Kp)[0];
        const float4 k1 = reinterpret_cast<const float4*>(Kp)[1];
        const float4 k2 = reinterpret_cast<const float4*>(Kp)[2];
        const float4 k3 = reinterpret_cast<const float4*>(Kp)[3];
        const float* P = &pose_lds[n * POSE_PAD];
        #pragma unroll
        for (int p = 0; p < 4; ++p) {
            const float p0 = P[p * 4 + 0], p1 = P[p * 4 + 1];
            const float p2 = P[p * 4 + 2], p3 = P[p * 4 + 3];
            const float e0 = p0 * k0.x + p1 * k1.x + p2 * k2.x + p3 * k3.x;
            const float e1 = p0 * k0.y + p1 * k1.y + p2 * k2.y + p3 * k3.y;
            const float e2 = p0 * k0.z + p1 * k1.z + p2 * k2.z + p3 * k3.z;
            const float e3 = p0 * k0.w + p1 * k1.w + p2 * k2.w + p3 * k3.w;
            vp[j][p * 2 + 0] = bf16rne(e0) | (bf16rne(e1) << 16);
            vp[j][p * 2 + 1] = bf16rne(e2) | (bf16rne(e3) << 16);
        }
    }

    float breg[VPT];
    #pragma unroll
    for (int j = 0; j < VPT; ++j) breg[j] = 0.0f;

    float s[16];   // partial sum, then squashed v

    #pragma unroll
    for (int iter = 0; iter < 3; ++iter) {
        // s[o] = sum_n c * vote, c = softmax_o(b)
        #pragma unroll
        for (int e = 0; e < 16; ++e) s[e] = 0.0f;
        #pragma unroll
        for (int j = 0; j < VPT; ++j) {
            float c;
            if (iter == 0) c = 1.0f / 16.0f;
            else {
                const int n = nt + 16 * j;
                c = __expf(breg[j] - nmax[n]) * rden[n];
            }
            #pragma unroll
            for (int pr = 0; pr < 8; ++pr) {
                const unsigned int pk = vp[j][pr];
                s[2 * pr + 0] += c * bf_lo(pk);
                s[2 * pr + 1] += c * bf_hi(pk);
            }
        }
        // reduce across the 16 lanes of this o-group
        #pragma unroll
        for (int m = 1; m <= 8; m <<= 1) {
            #pragma unroll
            for (int e = 0; e < 16; ++e) s[e] += __shfl_xor(s[e], m, 64);
        }

        // squash
        float sq = 0.0f;
        #pragma unroll
        for (int e = 0; e < 16; ++e) sq += s[e] * s[e];
        const float factor = (sq / (1.0f + sq)) * rsqrtf(sq + 1e-9f);
        #pragma unroll
        for (int e = 0; e < 16; ++e) s[e] *= factor;

        if (iter < 2) {
            // b += dot(v, vote); publish b for softmax stats
            #pragma unroll
            for (int j = 0; j < VPT; ++j) {
                float d = 0.0f;
                #pragma unroll
                for (int pr = 0; pr < 8; ++pr) {
                    const unsigned int pk = vp[j][pr];
                    d += s[2 * pr + 0] * bf_lo(pk);
                    d += s[2 * pr + 1] * bf_hi(pk);
                }
                breg[j] += d;
                b_lds[(nt + 16 * j) * B_PAD + o] = breg[j];
            }
            __syncthreads();
            if (t < N_VOTES) {
                float mx = -1e30f;
                #pragma unroll
                for (int oo = 0; oo < 16; ++oo)
                    mx = fmaxf(mx, b_lds[t * B_PAD + oo]);
                float sum = 0.0f;
                #pragma unroll
                for (int oo = 0; oo < 16; ++oo)
                    sum += __expf(b_lds[t * B_PAD + oo] - mx);
                nmax[t] = mx;
                rden[t] = 1.0f / sum;
            }
            __syncthreads();
        }
    }

    // ---- output ----
    // capsule_poses: [8,15,15,16,4,4] flat: site*256 + o*16 + e
    float vout = s[0];
    #pragma unroll
    for (int e = 1; e < 16; ++e) {
        if (nt == e) vout = s[e];
    }
    out[(size_t)site * 256 + t] = vout;

    // capsule_activations: [8,15,15,16] after poses (460800 floats)
    if (nt == 0) {
        float sqv = 0.0f;
        #pragma unroll
        for (int e = 0; e < 16; ++e) sqv += s[e] * s[e];
        out[460800 + (size_t)site * 16 + o] = sqrtf(sqv + 1e-12f);
    }
}

extern "C" void kernel_launch(void* const* d_in, const int* in_sizes, int n_in,
                              void* d_out, int out_size, void* d_ws, size_t ws_size,
                              hipStream_t stream) {
    const float* poses = (const float*)d_in[0];   // [8,32,32,16,4,4] f32
    // d_in[1] = input_activations: unused by the reference computation
    const float* kern  = (const float*)d_in[2];   // [16,3,3,16,4,4] f32
    float* outp = (float*)d_out;                  // 460800 poses + 28800 acts

    convcaps_routing_kernel<<<dim3(8 * OH * OW), dim3(256), 0, stream>>>(
        poses, kern, outp);
}